// Round 8
// baseline (613.348 us; speedup 1.0000x reference)
//
#include <hip/hip_runtime.h>
#include <math.h>

#define P 512
#define KC 10
#define NB 32
#define EPSV 0.01f
#define TR_ROWS 448
#define XT 17024   // padded columns: 16384 + per-class 64-alignment

typedef __attribute__((ext_vector_type(8))) __bf16 bf16x8;
typedef __attribute__((ext_vector_type(4))) float floatx4;

// ---------------- fused histogram + padded offsets + colmap scatter (one block) ----------------
__global__ __launch_bounds__(256) void sort_k(const int* __restrict__ Y, int* __restrict__ colmap,
                                              int* __restrict__ counts, int* __restrict__ off_pad,
                                              int* __restrict__ done, int m){
  __shared__ int cnt[KC], offp[KC + 1], cur[KC];
  int tid = threadIdx.x;
  if (tid == 0) *done = 0;
  if (tid < KC) cnt[tid] = 0;
  __syncthreads();
  for (int i = tid; i < m; i += 256){
    int y = Y[i];
    if (y >= 0 && y < KC) atomicAdd(&cnt[y], 1);
  }
  __syncthreads();
  if (tid == 0){
    int s = 0;
    for (int j = 0; j < KC; ++j){ offp[j] = s; s += ((cnt[j] + 63) >> 6) << 6; }
    offp[KC] = s;
  }
  __syncthreads();
  if (tid < KC){ cur[tid] = offp[tid]; counts[tid] = cnt[tid]; off_pad[tid] = offp[tid]; }
  if (tid == KC) off_pad[KC] = offp[KC];
  for (int i = tid; i < XT; i += 256) colmap[i] = -1;
  __syncthreads();
  for (int i = tid; i < m; i += 256){
    int y = Y[i];
    if (y >= 0 && y < KC){
      int pos = atomicAdd(&cur[y], 1);
      colmap[pos] = i;
    }
  }
}

// ---------------- transpose + split-bf16 convert: X[m][512] -> Xt_hi/lo[512][XT] ----------------
__global__ __launch_bounds__(256) void xt_k(const float* __restrict__ X, const int* __restrict__ colmap,
                                            __bf16* __restrict__ Xhi, __bf16* __restrict__ Xlo){
  __shared__ float T[64][65];
  int c0 = blockIdx.x * 64;
  int f0 = blockIdx.y * 64;
  int tid = threadIdx.x;

  int j = tid >> 2;
  int piece = tid & 3;
  int s = colmap[c0 + j];
  if (s >= 0){
    const float* src = X + (long)s * P + f0 + piece * 16;
    #pragma unroll
    for (int q = 0; q < 4; ++q){
      float4 v = *(const float4*)(src + q * 4);
      T[piece * 16 + q * 4 + 0][j] = v.x;
      T[piece * 16 + q * 4 + 1][j] = v.y;
      T[piece * 16 + q * 4 + 2][j] = v.z;
      T[piece * 16 + q * 4 + 3][j] = v.w;
    }
  } else {
    #pragma unroll
    for (int q = 0; q < 16; ++q) T[piece * 16 + q][j] = 0.f;
  }
  __syncthreads();

  int f = tid >> 2;
  int cp = (tid & 3) * 16;
  bf16x8 vh0, vl0, vh1, vl1;
  #pragma unroll
  for (int q = 0; q < 8; ++q){
    float x0 = T[f][cp + q];
    float x1 = T[f][cp + 8 + q];
    __bf16 h0 = (__bf16)x0, h1 = (__bf16)x1;
    vh0[q] = h0; vl0[q] = (__bf16)(x0 - (float)h0);
    vh1[q] = h1; vl1[q] = (__bf16)(x1 - (float)h1);
  }
  long base = (long)(f0 + f) * XT + c0 + cp;
  *(bf16x8*)&Xhi[base]     = vh0;
  *(bf16x8*)&Xhi[base + 8] = vh1;
  *(bf16x8*)&Xlo[base]     = vl0;
  *(bf16x8*)&Xlo[base + 8] = vl1;
}

// ---------------- per-class Gram via MFMA, split-bf16 ----------------
__global__ __launch_bounds__(256) void gram_mfma(const __bf16* __restrict__ Xhi,
                                                 const __bf16* __restrict__ Xlo,
                                                 const int* __restrict__ counts,
                                                 const int* __restrict__ off_pad,
                                                 float* __restrict__ Gk){
  int cls = blockIdx.y;
  int ta = 0, rem = blockIdx.x;
  while (rem >= ta + 1){ rem -= ta + 1; ++ta; }
  int tb = rem;
  int a0 = ta * 64, b0 = tb * 64;

  int tid  = threadIdx.x;
  int lane = tid & 63;
  int wv   = tid >> 6;
  int wrow = wv >> 1, wcol = wv & 1;
  int fr   = lane & 15;
  int quad = lane >> 4;

  int cs0     = off_pad[cls];
  int nchunks = (counts[cls] + 31) >> 5;

  long arow0 = (long)(a0 + wrow * 32 + fr) * XT;
  long brow0 = (long)(b0 + wcol * 32 + fr) * XT;

  floatx4 acc[2][2];
  #pragma unroll
  for (int i = 0; i < 2; ++i)
    #pragma unroll
    for (int j = 0; j < 2; ++j) acc[i][j] = (floatx4){0.f, 0.f, 0.f, 0.f};

  for (int ch = 0; ch < nchunks; ++ch){
    long co = cs0 + ch * 32 + quad * 8;
    bf16x8 ah[2], al[2], bh[2], bl[2];
    #pragma unroll
    for (int r = 0; r < 2; ++r){
      ah[r] = *(const bf16x8*)&Xhi[arow0 + (long)r * 16 * XT + co];
      al[r] = *(const bf16x8*)&Xlo[arow0 + (long)r * 16 * XT + co];
      bh[r] = *(const bf16x8*)&Xhi[brow0 + (long)r * 16 * XT + co];
      bl[r] = *(const bf16x8*)&Xlo[brow0 + (long)r * 16 * XT + co];
    }
    #pragma unroll
    for (int ri = 0; ri < 2; ++ri)
      #pragma unroll
      for (int rj = 0; rj < 2; ++rj){
        acc[ri][rj] = __builtin_amdgcn_mfma_f32_16x16x32_bf16(al[ri], bh[rj], acc[ri][rj], 0, 0, 0);
        acc[ri][rj] = __builtin_amdgcn_mfma_f32_16x16x32_bf16(ah[ri], bl[rj], acc[ri][rj], 0, 0, 0);
        acc[ri][rj] = __builtin_amdgcn_mfma_f32_16x16x32_bf16(ah[ri], bh[rj], acc[ri][rj], 0, 0, 0);
      }
  }

  float* C = Gk + (long)cls * P * P;
  #pragma unroll
  for (int ri = 0; ri < 2; ++ri){
    int a = a0 + wrow * 32 + ri * 16 + (lane >> 4) * 4;
    #pragma unroll
    for (int rj = 0; rj < 2; ++rj){
      int b = b0 + wcol * 32 + rj * 16 + (lane & 15);
      #pragma unroll
      for (int r = 0; r < 4; ++r)
        C[(long)(a + r) * P + b] = acc[ri][rj][r];
    }
  }
}

// ---------------- slot 10 = sum of class Grams ----------------
__global__ __launch_bounds__(256) void sum10_k(float* __restrict__ Gk){
  long i = (long)blockIdx.x * 256 + threadIdx.x;
  float4 s = {0.f, 0.f, 0.f, 0.f};
  #pragma unroll
  for (int j = 0; j < KC; ++j){
    float4 v = ((const float4*)(Gk + (long)j * P * P))[i];
    s.x += v.x; s.y += v.y; s.z += v.z; s.w += v.w;
  }
  ((float4*)(Gk + (long)KC * P * P))[i] = s;
}

// ---------------- single-block-per-matrix MFMA Cholesky logdet ----------------
// Per 32-step: wave-0 factors diag in registers (shfl) AND builds Minv=L11^-1
// (per-lane forward solve); trsm becomes L21 = A21*Minv^T via split-bf16 MFMA
// on all 16 waves; trailing syrk unchanged (MFMA, LDS bf16 hi/lo panel).
// Last-finished block computes the final outputs (done counter).
__global__ __launch_bounds__(1024) void chol_mfma(float* __restrict__ Gk,
                                                  const int* __restrict__ counts,
                                                  float* __restrict__ logdets,
                                                  int* __restrict__ done,
                                                  float* __restrict__ out,
                                                  float m_tot){
  __shared__ __bf16 Lhi[TR_ROWS * 32];
  __shared__ __bf16 Llo[TR_ROWS * 32];
  __shared__ float  Ld[NB * 33];
  __shared__ float  Ldr[NB];
  __shared__ float  Minv[NB * 36];   // Minv[r][c] = (L11^-1)[r][c], stride 36 (16B-aligned rows)

  int mat  = blockIdx.x;
  int tid  = threadIdx.x;
  int lane = tid & 63;
  int wv   = tid >> 6;
  int quad = lane >> 4;
  float* A = Gk + (long)mat * P * P;
  float sc = (mat < KC) ? ((float)P / (((float)counts[mat] + 1e-8f) * EPSV))
                        : ((float)P / (m_tot * EPSV));
  float logsum = 0.f;

  for (int s = 0; s < 16; ++s){
    int j0 = s * NB;
    int qt = P - j0 - NB;

    // ==== wave 0: diag factor + inverse + pivot logs ====
    if (wv == 0){
      float a[NB];
      float myp = 1.f;
      if (lane < NB){
        const float* src = A + (long)(j0 + lane) * P + j0;
        #pragma unroll
        for (int u = 0; u < NB; u += 4){
          float4 v = *(const float4*)(src + u);
          a[u] = v.x; a[u+1] = v.y; a[u+2] = v.z; a[u+3] = v.w;
        }
        if (s == 0){
          #pragma unroll
          for (int u = 0; u < NB; ++u) a[u] *= sc;
          a[lane] += 1.0f;
        }
      } else {
        #pragma unroll
        for (int u = 0; u < NB; ++u) a[u] = 0.f;
      }
      #pragma unroll
      for (int jj = 0; jj < NB; ++jj){
        float d = __shfl(a[jj], jj);
        if (lane == jj) myp = d;
        float inv = 1.0f / d;
        float rs  = rsqrtf(d);
        float w   = a[jj] * inv;
        #pragma unroll
        for (int l = jj + 1; l < NB; ++l){
          float prl = __shfl(a[l], jj);
          if (lane > jj) a[l] -= w * prl;
        }
        if (lane >= jj) a[jj] *= rs;
      }
      if (lane < NB){
        #pragma unroll
        for (int u = 0; u < NB; ++u) Ld[lane * 33 + u] = a[u];
        Ldr[lane] = 1.0f / a[lane];
      }
      // Minv: lane c solves L x = e_c (forward substitution, uniform Ld reads)
      if (lane < NB){
        float x[NB];
        #pragma unroll
        for (int r2 = 0; r2 < NB; ++r2){
          float acc2 = (r2 == lane) ? 1.f : 0.f;
          #pragma unroll
          for (int u = 0; u < r2; ++u)
            acc2 -= Ld[r2 * 33 + u] * x[u];
          x[r2] = acc2 * Ldr[r2];
        }
        #pragma unroll
        for (int r2 = 0; r2 < NB; ++r2) Minv[r2 * 36 + lane] = x[r2];
      }
      float lp = (lane < NB) ? logf(myp) : 0.f;
      #pragma unroll
      for (int off = 16; off >= 1; off >>= 1) lp += __shfl_xor(lp, off);
      if (tid == 0) logsum += lp;
    }
    __syncthreads();

    // ==== trsm via MFMA: L21 = A21 * Minv^T, written to LDS panel (bf16 hi/lo) ====
    if (qt > 0){
      int nrt = qt >> 4;   // 16-row tiles (qt is a multiple of 32)
      for (int rt = wv; rt < nrt; rt += 16){
        int grow = j0 + NB + rt * 16 + (lane & 15);
        const float* src = A + (long)grow * P + j0 + quad * 8;
        float4 v0 = *(const float4*)src;
        float4 v1 = *(const float4*)(src + 4);
        float av[8] = {v0.x, v0.y, v0.z, v0.w, v1.x, v1.y, v1.z, v1.w};
        if (s == 0){
          #pragma unroll
          for (int u = 0; u < 8; ++u) av[u] *= sc;   // strictly sub-diagonal: no +I
        }
        bf16x8 ah, al;
        #pragma unroll
        for (int u = 0; u < 8; ++u){
          __bf16 h = (__bf16)av[u];
          ah[u] = h; al[u] = (__bf16)(av[u] - (float)h);
        }
        #pragma unroll
        for (int h2 = 0; h2 < 2; ++h2){
          const float* mp = &Minv[(h2 * 16 + (lane & 15)) * 36 + quad * 8];
          float4 m0 = *(const float4*)mp;
          float4 m1 = *(const float4*)(mp + 4);
          float mv[8] = {m0.x, m0.y, m0.z, m0.w, m1.x, m1.y, m1.z, m1.w};
          bf16x8 bh, bl;
          #pragma unroll
          for (int u = 0; u < 8; ++u){
            __bf16 h = (__bf16)mv[u];
            bh[u] = h; bl[u] = (__bf16)(mv[u] - (float)h);
          }
          floatx4 acc = {0.f, 0.f, 0.f, 0.f};
          acc = __builtin_amdgcn_mfma_f32_16x16x32_bf16(al, bh, acc, 0, 0, 0);
          acc = __builtin_amdgcn_mfma_f32_16x16x32_bf16(ah, bl, acc, 0, 0, 0);
          acc = __builtin_amdgcn_mfma_f32_16x16x32_bf16(ah, bh, acc, 0, 0, 0);
          #pragma unroll
          for (int r = 0; r < 4; ++r){
            int t   = rt * 16 + quad * 4 + r;          // panel-local row
            int col = h2 * 16 + (lane & 15);           // panel col
            float y = acc[r];
            __bf16 hh = (__bf16)y;
            int ad = (t * 4 + ((col >> 3) ^ ((t >> 1) & 3))) * 8 + (col & 7);
            Lhi[ad] = hh;
            Llo[ad] = (__bf16)(y - (float)hh);
          }
        }
      }
    }
    __syncthreads();

    // ==== trailing syrk (MFMA, unchanged) ====
    if (qt > 0){
      int tt = qt >> 5;
      int T  = tt * (tt + 1) / 2;
      int trail0 = j0 + NB;
      for (int idx = wv; idx < T; idx += 16){
        int ti = 0, rem = idx;
        while (rem >= ti + 1){ rem -= ti + 1; ++ti; }
        int tj = rem;
        int I0 = ti * 32, J0 = tj * 32;
        int c  = quad;

        bf16x8 ahi[2], alo[2], bhi[2], blo[2];
        #pragma unroll
        for (int h = 0; h < 2; ++h){
          int r1 = I0 + h * 16 + (lane & 15);
          int sw1 = (r1 * 4 + (c ^ ((r1 >> 1) & 3))) * 8;
          ahi[h] = *(const bf16x8*)&Lhi[sw1];
          alo[h] = *(const bf16x8*)&Llo[sw1];
          int r2 = J0 + h * 16 + (lane & 15);
          int sw2 = (r2 * 4 + (c ^ ((r2 >> 1) & 3))) * 8;
          bhi[h] = *(const bf16x8*)&Lhi[sw2];
          blo[h] = *(const bf16x8*)&Llo[sw2];
        }

        #pragma unroll
        for (int hi_ = 0; hi_ < 2; ++hi_){
          #pragma unroll
          for (int hj = 0; hj < 2; ++hj){
            floatx4 acc = {0.f, 0.f, 0.f, 0.f};
            acc = __builtin_amdgcn_mfma_f32_16x16x32_bf16(alo[hi_], bhi[hj], acc, 0, 0, 0);
            acc = __builtin_amdgcn_mfma_f32_16x16x32_bf16(ahi[hi_], blo[hj], acc, 0, 0, 0);
            acc = __builtin_amdgcn_mfma_f32_16x16x32_bf16(ahi[hi_], bhi[hj], acc, 0, 0, 0);
            int grow0 = trail0 + I0 + hi_ * 16 + (lane >> 4) * 4;
            int gcol  = trail0 + J0 + hj  * 16 + (lane & 15);
            #pragma unroll
            for (int r = 0; r < 4; ++r){
              long off = (long)(grow0 + r) * P + gcol;
              float v = A[off];
              if (s == 0) v = sc * v + ((grow0 + r) == gcol ? 1.f : 0.f);
              A[off] = v - acc[r];
            }
          }
        }
      }
    }
    __syncthreads();
  }

  // ==== epilogue: publish logdet; last block computes outputs ====
  if (tid == 0){
    __hip_atomic_store(&logdets[mat], logsum, __ATOMIC_RELEASE, __HIP_MEMORY_SCOPE_AGENT);
    int old = __hip_atomic_fetch_add(done, 1, __ATOMIC_ACQ_REL, __HIP_MEMORY_SCOPE_AGENT);
    if (old == KC){
      float ld[KC + 1];
      #pragma unroll
      for (int j = 0; j <= KC; ++j)
        ld[j] = __hip_atomic_load(&logdets[j], __ATOMIC_ACQUIRE, __HIP_MEMORY_SCOPE_AGENT);
      out[0] = 0.5f * ld[KC];
      float comp = 0.f;
      for (int j = 0; j < KC; ++j){
        float trPi = (float)counts[j] + 1e-8f;
        comp += ld[j] * trPi / m_tot;
      }
      out[1] = 0.5f * comp;
    }
  }
}

extern "C" void kernel_launch(void* const* d_in, const int* in_sizes, int n_in,
                              void* d_out, int out_size, void* d_ws, size_t ws_size,
                              hipStream_t stream) {
  (void)n_in; (void)out_size; (void)ws_size;
  const float* X = (const float*)d_in[0];
  const int*   Y = (const int*)d_in[1];
  int m = in_sizes[0] / P;     // 16384

  float*  Gk      = (float*)d_ws;                    // 11 * P*P floats
  __bf16* Xhi     = (__bf16*)(Gk + 11L * P * P);     // 512*XT bf16
  __bf16* Xlo     = Xhi + (long)P * XT;              // 512*XT bf16
  int*    colmap  = (int*)(Xlo + (long)P * XT);      // XT ints
  int*    counts  = colmap + XT;                     // 16
  int*    off_pad = counts + 16;                     // 17
  int*    done    = off_pad + 17;                    // 1
  float*  logdets = (float*)(done + 1);              // 16

  sort_k<<<1, 256, 0, stream>>>(Y, colmap, counts, off_pad, done, m);

  dim3 xg(XT / 64, 8);
  xt_k<<<xg, 256, 0, stream>>>(X, colmap, Xhi, Xlo);

  dim3 gg(36, KC);
  gram_mfma<<<gg, 256, 0, stream>>>(Xhi, Xlo, counts, off_pad, Gk);

  sum10_k<<<P * P / 1024, 256, 0, stream>>>(Gk);

  chol_mfma<<<KC + 1, 1024, 0, stream>>>(Gk, counts, logdets, done, (float*)d_out, (float)m);
}